// Round 4
// baseline (88.373 us; speedup 1.0000x reference)
//
#include <hip/hip_runtime.h>

// VQ linear: out[b][o] = sum_k x[b][k] * dq[o][k]
// dq[o][k]: word = qweight[o][k/16]; nibble = (k/2)%8; idx = (word>>(4*nibble))&15;
//           dq[o][k] = lut[idx][k%2]
// Device dtypes (harness promotes reference f16 -> f32):
//   x (16,8192) f32, qweight (8192,512) i32, lut (16,2) f32, out (16,8192) f32.
// Values are exactly f16-representable, so f32->f16 conversion is lossless and
// mfma_f32_16x16x32_f16 with f32 accumulate reproduces the reference.

typedef _Float16 half8 __attribute__((ext_vector_type(8)));
typedef _Float16 half4_t __attribute__((ext_vector_type(4)));
typedef float float4_t __attribute__((ext_vector_type(4)));

#define O_FEAT 8192
#define I_FEAT 8192
#define WAVES 16
#define K_PER_WAVE (I_FEAT / WAVES)   // 512
#define ITERS (K_PER_WAVE / 32)       // 16 MFMA K-steps per wave
#define TILES 2                       // 32 outputs per block

// ---- pre-kernel: convert x f32 -> f16 into workspace (lossless) ----
__global__ void cvt_x_kernel(const float* __restrict__ x, _Float16* __restrict__ xf) {
    int i = (blockIdx.x * 256 + threadIdx.x) * 8;
    float4_t f0 = *(const float4_t*)(x + i);
    float4_t f1 = *(const float4_t*)(x + i + 4);
    half8 h = { (_Float16)f0[0], (_Float16)f0[1], (_Float16)f0[2], (_Float16)f0[3],
                (_Float16)f1[0], (_Float16)f1[1], (_Float16)f1[2], (_Float16)f1[3] };
    *(half8*)(xf + i) = h;
}

// ---- main kernel ----
template <bool XF16>
__launch_bounds__(1024, 4)
__global__ void vq_gemm_kernel(const void* __restrict__ xsrc,
                               const unsigned short* __restrict__ qw,   // qweight as u16
                               const float* __restrict__ lutf,          // lut (16,2) f32
                               float* __restrict__ out) {
    // Byte-pair dequant table: byte v -> 4 f16 {lut[v&15].xy, lut[v>>4].xy}
    __shared__ half4_t pairlut[256];
    __shared__ float red[WAVES][TILES * 256];

    const int tid = threadIdx.x;
    if (tid < 256) {
        half4_t v;
        v[0] = (_Float16)lutf[(tid & 15) * 2 + 0];
        v[1] = (_Float16)lutf[(tid & 15) * 2 + 1];
        v[2] = (_Float16)lutf[(tid >> 4) * 2 + 0];
        v[3] = (_Float16)lutf[(tid >> 4) * 2 + 1];
        pairlut[tid] = v;
    }
    __syncthreads();

    const int wave = tid >> 6;
    const int lane = tid & 63;
    const int ln15 = lane & 15;   // A: batch row m; B: output col n within tile
    const int kgrp = lane >> 4;   // k-group: 8 contiguous k at kgrp*8 within K=32 window

    const int obase = blockIdx.x * (TILES * 16);
    const int k0 = wave * K_PER_WAVE;

    // x fragment source: row ln15, elements [k0 + kgrp*8, +8)
    const int xoff = ln15 * I_FEAT + k0 + kgrp * 8;
    // qweight: 1024 u16 per row; u16 index within row = k/8 (little-endian halves)
    const unsigned short* qp0 = qw + (obase + ln15) * 1024 + (k0 >> 3) + kgrp;
    const unsigned short* qp1 = qp0 + 16 * 1024;   // second 16-output tile

    float4_t acc0 = {0.f, 0.f, 0.f, 0.f};
    float4_t acc1 = {0.f, 0.f, 0.f, 0.f};

#pragma unroll 4
    for (int it = 0; it < ITERS; ++it) {
        half8 a;
        if constexpr (XF16) {
            a = *(const half8*)((const _Float16*)xsrc + xoff + it * 32);
        } else {
            const float* xp = (const float*)xsrc + xoff + it * 32;
            float4_t f0 = *(const float4_t*)xp;
            float4_t f1 = *(const float4_t*)(xp + 4);
            a = (half8){ (_Float16)f0[0], (_Float16)f0[1], (_Float16)f0[2], (_Float16)f0[3],
                         (_Float16)f1[0], (_Float16)f1[1], (_Float16)f1[2], (_Float16)f1[3] };
        }
        unsigned int q0 = qp0[it * 4];   // 16 bits = 4 nibbles = 8 k-elements
        unsigned int q1 = qp1[it * 4];
        half4_t p00 = pairlut[q0 & 0xFF];
        half4_t p01 = pairlut[(q0 >> 8) & 0xFF];
        half4_t p10 = pairlut[q1 & 0xFF];
        half4_t p11 = pairlut[(q1 >> 8) & 0xFF];
        half8 b0 = __builtin_shufflevector(p00, p01, 0, 1, 2, 3, 4, 5, 6, 7);
        half8 b1 = __builtin_shufflevector(p10, p11, 0, 1, 2, 3, 4, 5, 6, 7);
        acc0 = __builtin_amdgcn_mfma_f32_16x16x32_f16(a, b0, acc0, 0, 0, 0);
        acc1 = __builtin_amdgcn_mfma_f32_16x16x32_f16(a, b1, acc1, 0, 0, 0);
    }

    // Cross-wave K reduction via LDS.
    // D layout: col n = lane&15, row m = (lane>>4)*4 + r
#pragma unroll
    for (int r = 0; r < 4; ++r) {
        red[wave][0 * 256 + (kgrp * 4 + r) * 16 + ln15] = acc0[r];
        red[wave][1 * 256 + (kgrp * 4 + r) * 16 + ln15] = acc1[r];
    }
    __syncthreads();

    if (tid < TILES * 256) {
        float s = 0.f;
#pragma unroll
        for (int w = 0; w < WAVES; ++w)
            s += red[w][tid];
        const int t = tid >> 8;
        const int m = (tid >> 4) & 15;
        const int n = tid & 15;
        out[m * O_FEAT + obase + t * 16 + n] = s;
    }
}

extern "C" void kernel_launch(void* const* d_in, const int* in_sizes, int n_in,
                              void* d_out, int out_size, void* d_ws, size_t ws_size,
                              hipStream_t stream) {
    const float* x = (const float*)d_in[0];
    const unsigned short* qw = (const unsigned short*)d_in[1];
    const float* lutf = (const float*)d_in[2];
    float* out = (float*)d_out;

    dim3 grid(O_FEAT / (TILES * 16));   // 256 blocks of 32 outputs
    dim3 block(1024);                   // 16 waves: 16-way K split

    if (ws_size >= (size_t)(16 * I_FEAT * 2)) {
        // lossless x f32->f16 into workspace, then f16-reading main kernel
        cvt_x_kernel<<<dim3(16 * I_FEAT / (256 * 8)), dim3(256), 0, stream>>>(x, (_Float16*)d_ws);
        vq_gemm_kernel<true><<<grid, block, 0, stream>>>(d_ws, qw, lutf, out);
    } else {
        vq_gemm_kernel<false><<<grid, block, 0, stream>>>(x, qw, lutf, out);
    }
}

// Round 8
// 81.075 us; speedup vs baseline: 1.0900x; 1.0900x over previous
//
#include <hip/hip_runtime.h>

// VQ linear: out[b][o] = sum_k x[b][k] * dq[o][k]
// dq[o][k]: word = qweight[o][k/16]; nibble = (k/2)%8; idx = (word>>(4*nibble))&15;
//           dq[o][k] = lut[idx][k%2]
// Device dtypes (harness promotes reference f16 -> f32):
//   x (16,8192) f32, qweight (8192,512) i32, lut (16,2) f32, out (16,8192) f32.
// Values are exactly f16-representable -> lossless f32->f16, f16 MFMA, f32 accum.
//
// K-mapping trick: within a wave's 512-half K-slice (= 64 u16 per row), lane
// group g (= lane>>4) owns u16 indices [16g, 16g+16) contiguously, loaded as
// two dwordx4 per tile up front. MFMA step j uses per-lane u16 (16g + j); the
// x A-fragment loads the matching k range [wave*512 + 128g + 8j, +8). A and B
// agree on the (g,j)->k permutation, and summation over k is order-invariant.

typedef _Float16 half8 __attribute__((ext_vector_type(8)));
typedef _Float16 half4_t __attribute__((ext_vector_type(4)));
typedef float float4_t __attribute__((ext_vector_type(4)));
typedef unsigned int uint4_t __attribute__((ext_vector_type(4)));

#define O_FEAT 8192
#define I_FEAT 8192
#define WAVES 16
#define K_PER_WAVE (I_FEAT / WAVES)   // 512 halves = 64 u16 per row per wave
#define NJ (K_PER_WAVE / 32)          // 16 MFMA K-steps per wave
#define TILES 2                       // 32 outputs per block

// ---- pre-kernel: convert x f32 -> f16 into workspace (lossless) ----
__global__ void cvt_x_kernel(const float* __restrict__ x, _Float16* __restrict__ xf) {
    int i = (blockIdx.x * 256 + threadIdx.x) * 8;
    float4_t f0 = *(const float4_t*)(x + i);
    float4_t f1 = *(const float4_t*)(x + i + 4);
    half8 h = { (_Float16)f0[0], (_Float16)f0[1], (_Float16)f0[2], (_Float16)f0[3],
                (_Float16)f1[0], (_Float16)f1[1], (_Float16)f1[2], (_Float16)f1[3] };
    *(half8*)(xf + i) = h;
}

template <bool XF16>
__launch_bounds__(1024, 4)
__global__ void vq_gemm_kernel(const void* __restrict__ xsrc,
                               const unsigned char* __restrict__ qwb,  // qweight bytes
                               const float* __restrict__ lutf,         // lut (16,2) f32
                               float* __restrict__ out) {
    // Byte-pair dequant table: byte v -> 4 f16 {lut[v&15].xy, lut[v>>4].xy}
    __shared__ half4_t pairlut[256];
    __shared__ float4_t red[WAVES][TILES * 64];

    const int tid = threadIdx.x;
    if (tid < 256) {
        half4_t v;
        v[0] = (_Float16)lutf[(tid & 15) * 2 + 0];
        v[1] = (_Float16)lutf[(tid & 15) * 2 + 1];
        v[2] = (_Float16)lutf[(tid >> 4) * 2 + 0];
        v[3] = (_Float16)lutf[(tid >> 4) * 2 + 1];
        pairlut[tid] = v;
    }

    const int wave = tid >> 6;
    const int lane = tid & 63;
    const int ln15 = lane & 15;   // A: batch row; B: output col within tile
    const int g    = lane >> 4;   // k-group 0..3

    const int obase = blockIdx.x * (TILES * 16);

    // qweight row = 2048 B; wave slice = 128 B; lane chunk = 32 B (contiguous)
    const unsigned char* qp0 = qwb + (size_t)(obase + ln15) * 2048 + wave * 128 + g * 32;
    const unsigned char* qp1 = qp0 + 16 * 2048;   // second 16-output tile

    uint4_t qa0 = *(const uint4_t*)(qp0);        // u16 idx 16g+0..7  (j=0..7)
    uint4_t qb0 = *(const uint4_t*)(qp0 + 16);   // u16 idx 16g+8..15 (j=8..15)
    uint4_t qa1 = *(const uint4_t*)(qp1);
    uint4_t qb1 = *(const uint4_t*)(qp1 + 16);

    const int xoff = ln15 * I_FEAT + wave * K_PER_WAVE + 128 * g;

    __syncthreads();   // pairlut ready

    float4_t acc0 = {0.f, 0.f, 0.f, 0.f};
    float4_t acc1 = {0.f, 0.f, 0.f, 0.f};

#pragma unroll
    for (int j = 0; j < NJ; ++j) {
        half8 a;
        if constexpr (XF16) {
            a = *(const half8*)((const _Float16*)xsrc + xoff + 8 * j);
        } else {
            const float* xp = (const float*)xsrc + xoff + 8 * j;
            float4_t f0 = *(const float4_t*)xp;
            float4_t f1 = *(const float4_t*)(xp + 4);
            a = (half8){ (_Float16)f0[0], (_Float16)f0[1], (_Float16)f0[2], (_Float16)f0[3],
                         (_Float16)f1[0], (_Float16)f1[1], (_Float16)f1[2], (_Float16)f1[3] };
        }
        // u16 (16g + j): j<8 in qa*, j>=8 in qb*; odd j = high half of the u32.
        unsigned int w0 = (j < 8) ? qa0[(j >> 1) & 3] : qb0[(j >> 1) & 3];
        unsigned int w1 = (j < 8) ? qa1[(j >> 1) & 3] : qb1[(j >> 1) & 3];
        if (j & 1) { w0 >>= 16; w1 >>= 16; }
        half4_t p00 = pairlut[w0 & 0xFF];          // k-offsets 0..3
        half4_t p01 = pairlut[(w0 >> 8) & 0xFF];   // k-offsets 4..7
        half4_t p10 = pairlut[w1 & 0xFF];
        half4_t p11 = pairlut[(w1 >> 8) & 0xFF];
        half8 b0 = __builtin_shufflevector(p00, p01, 0, 1, 2, 3, 4, 5, 6, 7);
        half8 b1 = __builtin_shufflevector(p10, p11, 0, 1, 2, 3, 4, 5, 6, 7);
        acc0 = __builtin_amdgcn_mfma_f32_16x16x32_f16(a, b0, acc0, 0, 0, 0);
        acc1 = __builtin_amdgcn_mfma_f32_16x16x32_f16(a, b1, acc1, 0, 0, 0);
    }

    // Cross-wave K reduction via LDS (b128 writes, conflict-free).
    red[wave][lane] = acc0;
    red[wave][64 + lane] = acc1;
    __syncthreads();

    if (tid < 512) {
        const float* rf = (const float*)red;
        float s = 0.f;
#pragma unroll
        for (int w = 0; w < WAVES; ++w)
            s += rf[w * (TILES * 64 * 4) + tid];
        // tid -> (tile, lane, reg): D col n = lane&15, row m = (lane>>4)*4 + reg
        const int t2 = tid >> 8;
        const int l  = (tid >> 2) & 63;
        const int r  = tid & 3;
        const int m  = (l >> 4) * 4 + r;
        const int n  = l & 15;
        out[m * O_FEAT + obase + t2 * 16 + n] = s;
    }
}

extern "C" void kernel_launch(void* const* d_in, const int* in_sizes, int n_in,
                              void* d_out, int out_size, void* d_ws, size_t ws_size,
                              hipStream_t stream) {
    const float* x = (const float*)d_in[0];
    const unsigned char* qwb = (const unsigned char*)d_in[1];
    const float* lutf = (const float*)d_in[2];
    float* out = (float*)d_out;

    dim3 grid(O_FEAT / (TILES * 16));   // 256 blocks of 32 outputs (1 per CU)
    dim3 block(1024);                   // 16 waves: 16-way K split

    if (ws_size >= (size_t)(16 * I_FEAT * 2)) {
        cvt_x_kernel<<<dim3(16 * I_FEAT / (256 * 8)), dim3(256), 0, stream>>>(x, (_Float16*)d_ws);
        vq_gemm_kernel<true><<<grid, block, 0, stream>>>(d_ws, qwb, lutf, out);
    } else {
        vq_gemm_kernel<false><<<grid, block, 0, stream>>>(x, qwb, lutf, out);
    }
}